// Round 15
// baseline (277.539 us; speedup 1.0000x reference)
//
#include <hip/hip_runtime.h>

// GraphConv x2, CSR-pull + FUSED f16 MFMA GEMMs (R15):
//   wcast/xcast -> f16 staging (row-major)
//   CSR build: atomic-free 2-level counting sort (R11)
//   pull_h128: aggh = sum xh[srcs]          (R9, 62us = gather floor)
//   mfma_fused v2: 8 waves x 16 rows, A-frags register-prefetched, full
//     unroll; layer1 -> swizzled LDS tile -> layer2; hr(f16) + out(f32)
//   pull_add_h64: out += sum hr[srcs]       (R9)
//
// R15 rationale: R14's fused gemm = 70us with MfmaUtil 5%, 378 GB/s fetch,
// occupancy 15.6% — unroll-1 K-loop exposed A-load latency (2 loads in
// flight) and 4 waves/block gave no TLP. v2: prefetch all 8 A-frags (8
// independent loads), full unroll (compiler pipelines L2-hot B loads),
// 8 waves/block doubles resident waves. acc f4[8] per layer keeps VGPR sane.

typedef float f4 __attribute__((ext_vector_type(4)));
typedef _Float16 h8 __attribute__((ext_vector_type(8)));
typedef _Float16 h2 __attribute__((ext_vector_type(2)));

#define NB   1024    // coarse buckets (dst>>7); requires N <= 131072
#define EPB  4096    // edges per block in s1/s3; nblk = ceil(E/EPB) <= 512

__device__ __forceinline__ float2 h2f(unsigned u) {
    h2 p = __builtin_bit_cast(h2, u);
    float2 r; r.x = (float)p[0]; r.y = (float)p[1];
    return r;
}
__device__ __forceinline__ unsigned f2h(float a, float b) {
    h2 p; p[0] = (_Float16)a; p[1] = (_Float16)b;
    return __builtin_bit_cast(unsigned, p);
}

// ---------------------------- casts ----------------------------------------
// wbuf layout (halves): wr1h @0 [128x128] | wq1h @16384 | wr2h @32768 [64x128]
// | wq2h @40960  (total 49152)
__global__ void wcast(const float* __restrict__ wr1, const float* __restrict__ wq1,
                      const float* __restrict__ wr2, const float* __restrict__ wq2,
                      _Float16* __restrict__ wb)
{
    int i = blockIdx.x * 256 + threadIdx.x;
    if (i < 16384)      wb[i] = (_Float16)wr1[i];
    else if (i < 32768) wb[i] = (_Float16)wq1[i - 16384];
    else if (i < 40960) wb[i] = (_Float16)wr2[i - 32768];
    else if (i < 49152) wb[i] = (_Float16)wq2[i - 40960];
}

__global__ void xcast(const float* __restrict__ x, _Float16* __restrict__ xh,
                      long n)   // n = N*128, multiple of 8
{
    long i = (long)(blockIdx.x * 256 + threadIdx.x) * 8;
    if (i >= n) return;
    f4 a = *(const f4*)(x + i);
    f4 b = *(const f4*)(x + i + 4);
    h8 o;
    o[0] = (_Float16)a[0]; o[1] = (_Float16)a[1];
    o[2] = (_Float16)a[2]; o[3] = (_Float16)a[3];
    o[4] = (_Float16)b[0]; o[5] = (_Float16)b[1];
    o[6] = (_Float16)b[2]; o[7] = (_Float16)b[3];
    *(h8*)(xh + i) = o;
}

// ------------------ CSR build: atomic-free counting sort --------------------
__global__ __launch_bounds__(256) void s1_hist(const int* __restrict__ dst,
                                               int* __restrict__ mat, int E)
{
    __shared__ int hist[NB];
    const int tid = threadIdx.x;
    for (int i = tid; i < NB; i += 256) hist[i] = 0;
    __syncthreads();
    const int e0 = blockIdx.x * EPB;
#pragma unroll
    for (int it = 0; it < EPB / 256; ++it) {
        int e = e0 + it * 256 + tid;
        if (e < E) atomicAdd(&hist[dst[e] >> 7], 1);
    }
    __syncthreads();
    int* row = mat + (size_t)blockIdx.x * NB;
    for (int i = tid; i < NB; i += 256) row[i] = hist[i];
}

__global__ __launch_bounds__(512) void s2_colscan(int* __restrict__ mat,
                                                  int* __restrict__ tot, int nblk)
{
    __shared__ int ts[512];
    const int tid = threadIdx.x;
    const int b = blockIdx.x;
    int v = (tid < nblk) ? mat[(size_t)tid * NB + b] : 0;
    ts[tid] = v;
    __syncthreads();
#pragma unroll
    for (int off = 1; off < 512; off <<= 1) {
        int add = (tid >= off) ? ts[tid - off] : 0;
        __syncthreads();
        ts[tid] += add;
        __syncthreads();
    }
    if (tid < nblk) mat[(size_t)tid * NB + b] = ts[tid] - v;
    if (tid == 511) tot[b] = ts[511];
}

__global__ __launch_bounds__(NB) void s2b_base(const int* __restrict__ tot,
                                               int* __restrict__ bb,
                                               int* __restrict__ row_ptr,
                                               int N, int E)
{
    __shared__ int ts[NB];
    const int tid = threadIdx.x;
    int v = tot[tid];
    ts[tid] = v;
    __syncthreads();
#pragma unroll
    for (int off = 1; off < NB; off <<= 1) {
        int add = (tid >= off) ? ts[tid - off] : 0;
        __syncthreads();
        ts[tid] += add;
        __syncthreads();
    }
    bb[tid] = ts[tid] - v;
    if (tid == NB - 1) { bb[NB] = ts[NB - 1]; row_ptr[N] = E; }
}

__global__ __launch_bounds__(256) void s3_scatter(const int* __restrict__ src,
                                                  const int* __restrict__ dst,
                                                  const int* __restrict__ mat,
                                                  const int* __restrict__ bb,
                                                  unsigned* __restrict__ coarse, int E)
{
    __shared__ int cur[NB];
    const int tid = threadIdx.x;
    const int* mrow = mat + (size_t)blockIdx.x * NB;
    for (int i = tid; i < NB; i += 256) cur[i] = bb[i] + mrow[i];
    __syncthreads();
    const int e0 = blockIdx.x * EPB;
#pragma unroll
    for (int it = 0; it < EPB / 256; ++it) {
        int e = e0 + it * 256 + tid;
        if (e < E) {
            int d = dst[e];
            int p = atomicAdd(&cur[d >> 7], 1);
            coarse[p] = ((unsigned)src[e] << 7) | (unsigned)(d & 127);
        }
    }
}

__global__ __launch_bounds__(256) void s4_fine(const unsigned* __restrict__ coarse,
                                               const int* __restrict__ bb,
                                               int* __restrict__ row_ptr,
                                               int* __restrict__ srcs, int N)
{
    __shared__ int fcnt[128];
    __shared__ int fs[128];
    __shared__ int cur[128];
    const int tid = threadIdx.x;
    const int b = blockIdx.x;
    const int seg0 = bb[b], seg1 = bb[b + 1];
    if (tid < 128) fcnt[tid] = 0;
    __syncthreads();
    for (int p = seg0 + tid; p < seg1; p += 256)
        atomicAdd(&fcnt[coarse[p] & 127u], 1);
    __syncthreads();
    if (tid < 128) fs[tid] = fcnt[tid];
    __syncthreads();
#pragma unroll
    for (int off = 1; off < 128; off <<= 1) {
        int add = 0;
        if (tid < 128 && tid >= off) add = fs[tid - off];
        __syncthreads();
        if (tid < 128) fs[tid] += add;
        __syncthreads();
    }
    if (tid < 128) {
        int excl = fs[tid] - fcnt[tid];
        cur[tid] = seg0 + excl;
        int d = b * 128 + tid;
        if (d < N) row_ptr[d] = seg0 + excl;
    }
    __syncthreads();
    for (int p = seg0 + tid; p < seg1; p += 256) {
        unsigned v = coarse[p];
        int q = atomicAdd(&cur[v & 127u], 1);
        srcs[q] = (int)(v >> 7);
    }
}

// --------------------------- pull kernels (R9 versions) ---------------------
__global__ __launch_bounds__(256) void pull_h128(const uint2* __restrict__ xh4,
                                                 const int* __restrict__ row_ptr,
                                                 const int* __restrict__ srcs,
                                                 uint2* __restrict__ aggh4, int N)
{
    const int w    = (blockIdx.x * 256 + threadIdx.x) >> 6;
    const int l    = threadIdx.x & 63;
    const int half = l >> 5;
    const int col  = l & 31;
    if (w >= N) return;
    const int beg = row_ptr[w], end = row_ptr[w + 1];
    float a0 = 0.f, a1 = 0.f, a2 = 0.f, a3 = 0.f;
    int j = beg;
    for (; j + 7 < end; j += 8) {
        int s0 = srcs[j + 0 + half], s1 = srcs[j + 2 + half];
        int s2 = srcs[j + 4 + half], s3 = srcs[j + 6 + half];
        uint2 u0 = xh4[(size_t)s0 * 32 + col];
        uint2 u1 = xh4[(size_t)s1 * 32 + col];
        uint2 u2 = xh4[(size_t)s2 * 32 + col];
        uint2 u3 = xh4[(size_t)s3 * 32 + col];
        float2 p;
        p = h2f(u0.x); a0 += p.x; a1 += p.y;  p = h2f(u0.y); a2 += p.x; a3 += p.y;
        p = h2f(u1.x); a0 += p.x; a1 += p.y;  p = h2f(u1.y); a2 += p.x; a3 += p.y;
        p = h2f(u2.x); a0 += p.x; a1 += p.y;  p = h2f(u2.y); a2 += p.x; a3 += p.y;
        p = h2f(u3.x); a0 += p.x; a1 += p.y;  p = h2f(u3.y); a2 += p.x; a3 += p.y;
    }
    for (; j < end; j += 2) {
        int jj = j + half;
        float m = (jj < end) ? 1.f : 0.f;
        int s = srcs[(jj < end) ? jj : (end - 1)];
        uint2 u = xh4[(size_t)s * 32 + col];
        float2 p;
        p = h2f(u.x); a0 += m * p.x; a1 += m * p.y;
        p = h2f(u.y); a2 += m * p.x; a3 += m * p.y;
    }
    a0 += __shfl_xor(a0, 32); a1 += __shfl_xor(a1, 32);
    a2 += __shfl_xor(a2, 32); a3 += __shfl_xor(a3, 32);
    if (half == 0) {
        uint2 o; o.x = f2h(a0, a1); o.y = f2h(a2, a3);
        aggh4[(size_t)w * 32 + col] = o;
    }
}

__global__ __launch_bounds__(256) void pull_add_h64(const uint2* __restrict__ hr4,
                                                    const int* __restrict__ row_ptr,
                                                    const int* __restrict__ srcs,
                                                    float* __restrict__ out, int N)
{
    const int w   = (blockIdx.x * 256 + threadIdx.x) >> 6;
    const int l   = threadIdx.x & 63;
    const int q   = l >> 4;
    const int col = l & 15;
    if (w >= N) return;
    const int beg = row_ptr[w], end = row_ptr[w + 1];
    float a0 = 0.f, a1 = 0.f, a2 = 0.f, a3 = 0.f;
    int j = beg;
    for (; j + 7 < end; j += 8) {
        int s0 = srcs[j + q], s1 = srcs[j + 4 + q];
        uint2 u0 = hr4[(size_t)s0 * 16 + col];
        uint2 u1 = hr4[(size_t)s1 * 16 + col];
        float2 p;
        p = h2f(u0.x); a0 += p.x; a1 += p.y;  p = h2f(u0.y); a2 += p.x; a3 += p.y;
        p = h2f(u1.x); a0 += p.x; a1 += p.y;  p = h2f(u1.y); a2 += p.x; a3 += p.y;
    }
    for (; j < end; j += 4) {
        int jj = j + q;
        float m = (jj < end) ? 1.f : 0.f;
        int s = srcs[(jj < end) ? jj : (end - 1)];
        uint2 u = hr4[(size_t)s * 16 + col];
        float2 p;
        p = h2f(u.x); a0 += m * p.x; a1 += m * p.y;
        p = h2f(u.y); a2 += m * p.x; a3 += m * p.y;
    }
    a0 += __shfl_xor(a0, 16); a1 += __shfl_xor(a1, 16);
    a2 += __shfl_xor(a2, 16); a3 += __shfl_xor(a3, 16);
    a0 += __shfl_xor(a0, 32); a1 += __shfl_xor(a1, 32);
    a2 += __shfl_xor(a2, 32); a3 += __shfl_xor(a3, 32);
    if (q == 0) {
        f4* po = (f4*)out + (size_t)w * 16 + col;
        f4 cur = *po;
        cur[0] += a0; cur[1] += a1; cur[2] += a2; cur[3] += a3;
        *po = cur;
    }
}

// ----------------------- FUSED MFMA GEMM v2 (layer1 + layer2) ---------------
// 512 threads = 8 waves; block = 128 rows; wave = 16 rows x 128 cols.
// A-frags prefetched to regs (8 independent loads); K-loops fully unrolled.
// LDS: per-wave 16x128 f16 tile, XOR-swizzled (f16idx = col ^ ((row&7)<<3)).
__global__ __launch_bounds__(512) void mfma_fused(
    const _Float16* __restrict__ aggh, const _Float16* __restrict__ xh,
    const _Float16* __restrict__ wb,   // wr1h@0, wq1h@16384, wr2h@32768, wq2h@40960
    const float* __restrict__ b1, const float* __restrict__ b2,
    _Float16* __restrict__ hrh, float* __restrict__ outp, int N)
{
    __shared__ _Float16 hs[8][16 * 128];   // 32 KB
    const int wv = threadIdx.x >> 6;
    const int l  = threadIdx.x & 63;
    const int lr = l & 15;
    const int kg = l >> 4;
    const int base = blockIdx.x * 128 + wv * 16;
    const int r0 = min(base + lr, N - 1);
    _Float16* hb = &hs[wv][0];

    // ---- prefetch all 8 A-frags (4 aggh + 4 xh), independent loads ----
    h8 afr[8];
#pragma unroll
    for (int c = 0; c < 4; ++c) {
        const int k0 = c * 32 + kg * 8;
        afr[c]     = *(const h8*)(aggh + (size_t)r0 * 128 + k0);
        afr[c + 4] = *(const h8*)(xh   + (size_t)r0 * 128 + k0);
    }

    // ---- layer 1: K=256 dual, fully unrolled ----
    f4 acc[8];
#pragma unroll
    for (int n = 0; n < 8; ++n) acc[n] = 0.f;
#pragma unroll
    for (int kk = 0; kk < 8; ++kk) {
        const _Float16* B = (kk < 4) ? wb : (wb + 16384);
        const int k0 = (kk & 3) * 32 + kg * 8;
#pragma unroll
        for (int n = 0; n < 8; ++n) {
            h8 bf = *(const h8*)(B + (size_t)(n * 16 + lr) * 128 + k0);
            acc[n] = __builtin_amdgcn_mfma_f32_16x16x32_f16(afr[kk], bf, acc[n], 0, 0, 0);
        }
    }

    // ---- relu+bias -> swizzled LDS tile ----
    const int ro = kg * 4;
#pragma unroll
    for (int n = 0; n < 8; ++n) {
        const int col = n * 16 + lr;
        const float bias = b1[col];
#pragma unroll
        for (int j = 0; j < 4; ++j) {
            const int row = ro + j;
            hb[row * 128 + (col ^ ((row & 7) << 3))] =
                (_Float16)fmaxf(acc[n][j] + bias, 0.f);
        }
    }
    __syncthreads();

    // ---- layer 2: K=128 from LDS, fully unrolled ----
    f4 acc2[8];
#pragma unroll
    for (int n = 0; n < 8; ++n) acc2[n] = 0.f;
#pragma unroll
    for (int kk = 0; kk < 4; ++kk) {
        const int k0 = kk * 32 + kg * 8;
        const int swz = (lr & 7) << 3;
        h8 a0 = *(const h8*)&hb[lr * 128 + (k0 ^ swz)];
#pragma unroll
        for (int n = 0; n < 8; ++n) {
            h8 bf = *(const h8*)(wb + 32768 + (size_t)(n * 16 + lr) * 128 + k0);
            acc2[n] = __builtin_amdgcn_mfma_f32_16x16x32_f16(a0, bf, acc2[n], 0, 0, 0);
        }
    }

    // ---- epilogue: cols 0..63 -> hr(f16), 64..127 -> out(f32)+b2 ----
#pragma unroll
    for (int n = 0; n < 8; ++n) {
        const int col = n * 16 + lr;
#pragma unroll
        for (int j = 0; j < 4; ++j) {
            int r = base + ro + j;
            if (r < N) {
                if (n < 4) {
                    hrh[(size_t)r * 64 + col] = (_Float16)acc2[n][j];
                } else {
                    outp[(size_t)r * 64 + (col - 64)] = acc2[n][j] + b2[col - 64];
                }
            }
        }
    }
}

extern "C" void kernel_launch(void* const* d_in, const int* in_sizes, int n_in,
                              void* d_out, int out_size, void* d_ws, size_t ws_size,
                              hipStream_t stream)
{
    const float* x       = (const float*)d_in[0];
    const int*   ei      = (const int*)d_in[1];
    const float* w_rel1  = (const float*)d_in[2];
    const float* b_rel1  = (const float*)d_in[3];
    const float* w_root1 = (const float*)d_in[4];
    const float* w_rel2  = (const float*)d_in[5];
    const float* b_rel2  = (const float*)d_in[6];
    const float* w_root2 = (const float*)d_in[7];
    float* out = (float*)d_out;

    const int N = in_sizes[0] / 128;
    const int E = in_sizes[1] / 2;
    const int* src = ei;        // edge_index[0]
    const int* dst = ei + E;    // edge_index[1]

    // workspace (~67 MB):
    //   xh [N*128 h] | aggh [N*128 h] (hrh aliases) | wbuf [49152 h]
    //   | srcs [E] | coarse [E u32] | mat [nblk*NB] | tot [NB] | bb [NB+1]
    //   | row_ptr [N+1]
    _Float16* xh    = (_Float16*)d_ws;
    _Float16* aggh  = xh + (size_t)N * 128;
    _Float16* hrh   = aggh;                         // alias: aggh dead after gemm
    _Float16* wbuf  = aggh + (size_t)N * 128;
    int*      srcs    = (int*)(wbuf + 49152);
    unsigned* coarse  = (unsigned*)(srcs + E);
    const int nblk    = (E + EPB - 1) / EPB;        // <= 512 (E <= 2M)
    int*      mat     = (int*)(coarse + E);         // nblk*NB
    int*      tot     = mat + (size_t)nblk * NB;    // NB
    int*      bb      = tot + NB;                   // NB+1
    int*      row_ptr = bb + (NB + 1);              // N+1

    // ---- f16 staging ----
    wcast<<<(49152 + 255) / 256, 256, 0, stream>>>(w_rel1, w_root1, w_rel2, w_root2, wbuf);
    xcast<<<(N * 128 / 8 + 255) / 256, 256, 0, stream>>>(x, xh, (long)N * 128);

    // ---- CSR build: atomic-free 2-level counting sort ----
    s1_hist   <<<nblk, 256, 0, stream>>>(dst, mat, E);
    s2_colscan<<<NB, 512, 0, stream>>>(mat, tot, nblk);
    s2b_base  <<<1, NB, 0, stream>>>(tot, bb, row_ptr, N, E);
    s3_scatter<<<nblk, 256, 0, stream>>>(src, dst, mat, bb, coarse, E);
    s4_fine   <<<NB, 256, 0, stream>>>(coarse, bb, row_ptr, srcs, N);

    // 1. aggh = pull-sum xh
    pull_h128<<<(N * 64 + 255) / 256, 256, 0, stream>>>(
        (const uint2*)xh, row_ptr, srcs, (uint2*)aggh, N);

    // 2. fused GEMMs: hr(f16) = relu(...)@Wr2^T ; out = relu(...)@Wq2^T + b2
    mfma_fused<<<(N + 127) / 128, 512, 0, stream>>>(
        aggh, xh, wbuf, b_rel1, b_rel2, hrh, out, N);

    // 3. out += pull-sum hr
    pull_add_h64<<<(N * 64 + 255) / 256, 256, 0, stream>>>(
        (const uint2*)hrh, row_ptr, srcs, out, N);
}

// Round 16
// 226.157 us; speedup vs baseline: 1.2272x; 1.2272x over previous
//
#include <hip/hip_runtime.h>

// GraphConv x2, CSR-pull + FUSED f16 MFMA GEMMs (R16):
//   wcast/xcast -> f16 staging (row-major)
//   CSR build: atomic-free 2-level counting sort (R11)
//   pull_h128: aggh = sum xh[srcs]          (R9, 62us = gather floor)
//   mfma_fused v3: ALL WEIGHTS IN LDS (96KB swizzled) + 32KB h-tile,
//     4 waves x 32 rows, A-frags prefetched under the weight staging,
//     B-frags via conflict-free ds_read_b128. 1 block/CU (128KB LDS).
//   pull_add_h64: out += sum hr[srcs]       (R9)
//
// R16 rationale: R14/R15 fused gemms streamed B from global every MFMA
// (~1KB through L1/L2 per MFMA); R15's VGPR collapse (44) serialized those
// ~300cy loads -> 105us at 3.5% MfmaUtil. v3 moves the operand residency:
// weights (96KB f16 total) staged once per block into LDS with a 16B-slot
// XOR swizzle (slot ^= row&15 -> uniform 8/bank for b128 reads). LDS-pipe
// model: ~544KB/block / 128B/cy = 4.3k cy; x3.05 blocks/CU ~= 6-9us.

typedef float f4 __attribute__((ext_vector_type(4)));
typedef _Float16 h8 __attribute__((ext_vector_type(8)));
typedef _Float16 h2 __attribute__((ext_vector_type(2)));

#define NB   1024    // coarse buckets (dst>>7); requires N <= 131072
#define EPB  4096    // edges per block in s1/s3; nblk = ceil(E/EPB) <= 512

__device__ __forceinline__ float2 h2f(unsigned u) {
    h2 p = __builtin_bit_cast(h2, u);
    float2 r; r.x = (float)p[0]; r.y = (float)p[1];
    return r;
}
__device__ __forceinline__ unsigned f2h(float a, float b) {
    h2 p; p[0] = (_Float16)a; p[1] = (_Float16)b;
    return __builtin_bit_cast(unsigned, p);
}

// ---------------------------- casts ----------------------------------------
// wbuf layout (halves): wr1h @0 [128x128] | wq1h @16384 | wr2h @32768 [64x128]
// | wq2h @40960  (total 49152)
__global__ void wcast(const float* __restrict__ wr1, const float* __restrict__ wq1,
                      const float* __restrict__ wr2, const float* __restrict__ wq2,
                      _Float16* __restrict__ wb)
{
    int i = blockIdx.x * 256 + threadIdx.x;
    if (i < 16384)      wb[i] = (_Float16)wr1[i];
    else if (i < 32768) wb[i] = (_Float16)wq1[i - 16384];
    else if (i < 40960) wb[i] = (_Float16)wr2[i - 32768];
    else if (i < 49152) wb[i] = (_Float16)wq2[i - 40960];
}

__global__ void xcast(const float* __restrict__ x, _Float16* __restrict__ xh,
                      long n)   // n = N*128, multiple of 8
{
    long i = (long)(blockIdx.x * 256 + threadIdx.x) * 8;
    if (i >= n) return;
    f4 a = *(const f4*)(x + i);
    f4 b = *(const f4*)(x + i + 4);
    h8 o;
    o[0] = (_Float16)a[0]; o[1] = (_Float16)a[1];
    o[2] = (_Float16)a[2]; o[3] = (_Float16)a[3];
    o[4] = (_Float16)b[0]; o[5] = (_Float16)b[1];
    o[6] = (_Float16)b[2]; o[7] = (_Float16)b[3];
    *(h8*)(xh + i) = o;
}

// ------------------ CSR build: atomic-free counting sort --------------------
__global__ __launch_bounds__(256) void s1_hist(const int* __restrict__ dst,
                                               int* __restrict__ mat, int E)
{
    __shared__ int hist[NB];
    const int tid = threadIdx.x;
    for (int i = tid; i < NB; i += 256) hist[i] = 0;
    __syncthreads();
    const int e0 = blockIdx.x * EPB;
#pragma unroll
    for (int it = 0; it < EPB / 256; ++it) {
        int e = e0 + it * 256 + tid;
        if (e < E) atomicAdd(&hist[dst[e] >> 7], 1);
    }
    __syncthreads();
    int* row = mat + (size_t)blockIdx.x * NB;
    for (int i = tid; i < NB; i += 256) row[i] = hist[i];
}

__global__ __launch_bounds__(512) void s2_colscan(int* __restrict__ mat,
                                                  int* __restrict__ tot, int nblk)
{
    __shared__ int ts[512];
    const int tid = threadIdx.x;
    const int b = blockIdx.x;
    int v = (tid < nblk) ? mat[(size_t)tid * NB + b] : 0;
    ts[tid] = v;
    __syncthreads();
#pragma unroll
    for (int off = 1; off < 512; off <<= 1) {
        int add = (tid >= off) ? ts[tid - off] : 0;
        __syncthreads();
        ts[tid] += add;
        __syncthreads();
    }
    if (tid < nblk) mat[(size_t)tid * NB + b] = ts[tid] - v;
    if (tid == 511) tot[b] = ts[511];
}

__global__ __launch_bounds__(NB) void s2b_base(const int* __restrict__ tot,
                                               int* __restrict__ bb,
                                               int* __restrict__ row_ptr,
                                               int N, int E)
{
    __shared__ int ts[NB];
    const int tid = threadIdx.x;
    int v = tot[tid];
    ts[tid] = v;
    __syncthreads();
#pragma unroll
    for (int off = 1; off < NB; off <<= 1) {
        int add = (tid >= off) ? ts[tid - off] : 0;
        __syncthreads();
        ts[tid] += add;
        __syncthreads();
    }
    bb[tid] = ts[tid] - v;
    if (tid == NB - 1) { bb[NB] = ts[NB - 1]; row_ptr[N] = E; }
}

__global__ __launch_bounds__(256) void s3_scatter(const int* __restrict__ src,
                                                  const int* __restrict__ dst,
                                                  const int* __restrict__ mat,
                                                  const int* __restrict__ bb,
                                                  unsigned* __restrict__ coarse, int E)
{
    __shared__ int cur[NB];
    const int tid = threadIdx.x;
    const int* mrow = mat + (size_t)blockIdx.x * NB;
    for (int i = tid; i < NB; i += 256) cur[i] = bb[i] + mrow[i];
    __syncthreads();
    const int e0 = blockIdx.x * EPB;
#pragma unroll
    for (int it = 0; it < EPB / 256; ++it) {
        int e = e0 + it * 256 + tid;
        if (e < E) {
            int d = dst[e];
            int p = atomicAdd(&cur[d >> 7], 1);
            coarse[p] = ((unsigned)src[e] << 7) | (unsigned)(d & 127);
        }
    }
}

__global__ __launch_bounds__(256) void s4_fine(const unsigned* __restrict__ coarse,
                                               const int* __restrict__ bb,
                                               int* __restrict__ row_ptr,
                                               int* __restrict__ srcs, int N)
{
    __shared__ int fcnt[128];
    __shared__ int fs[128];
    __shared__ int cur[128];
    const int tid = threadIdx.x;
    const int b = blockIdx.x;
    const int seg0 = bb[b], seg1 = bb[b + 1];
    if (tid < 128) fcnt[tid] = 0;
    __syncthreads();
    for (int p = seg0 + tid; p < seg1; p += 256)
        atomicAdd(&fcnt[coarse[p] & 127u], 1);
    __syncthreads();
    if (tid < 128) fs[tid] = fcnt[tid];
    __syncthreads();
#pragma unroll
    for (int off = 1; off < 128; off <<= 1) {
        int add = 0;
        if (tid < 128 && tid >= off) add = fs[tid - off];
        __syncthreads();
        if (tid < 128) fs[tid] += add;
        __syncthreads();
    }
    if (tid < 128) {
        int excl = fs[tid] - fcnt[tid];
        cur[tid] = seg0 + excl;
        int d = b * 128 + tid;
        if (d < N) row_ptr[d] = seg0 + excl;
    }
    __syncthreads();
    for (int p = seg0 + tid; p < seg1; p += 256) {
        unsigned v = coarse[p];
        int q = atomicAdd(&cur[v & 127u], 1);
        srcs[q] = (int)(v >> 7);
    }
}

// --------------------------- pull kernels (R9 versions) ---------------------
__global__ __launch_bounds__(256) void pull_h128(const uint2* __restrict__ xh4,
                                                 const int* __restrict__ row_ptr,
                                                 const int* __restrict__ srcs,
                                                 uint2* __restrict__ aggh4, int N)
{
    const int w    = (blockIdx.x * 256 + threadIdx.x) >> 6;
    const int l    = threadIdx.x & 63;
    const int half = l >> 5;
    const int col  = l & 31;
    if (w >= N) return;
    const int beg = row_ptr[w], end = row_ptr[w + 1];
    float a0 = 0.f, a1 = 0.f, a2 = 0.f, a3 = 0.f;
    int j = beg;
    for (; j + 7 < end; j += 8) {
        int s0 = srcs[j + 0 + half], s1 = srcs[j + 2 + half];
        int s2 = srcs[j + 4 + half], s3 = srcs[j + 6 + half];
        uint2 u0 = xh4[(size_t)s0 * 32 + col];
        uint2 u1 = xh4[(size_t)s1 * 32 + col];
        uint2 u2 = xh4[(size_t)s2 * 32 + col];
        uint2 u3 = xh4[(size_t)s3 * 32 + col];
        float2 p;
        p = h2f(u0.x); a0 += p.x; a1 += p.y;  p = h2f(u0.y); a2 += p.x; a3 += p.y;
        p = h2f(u1.x); a0 += p.x; a1 += p.y;  p = h2f(u1.y); a2 += p.x; a3 += p.y;
        p = h2f(u2.x); a0 += p.x; a1 += p.y;  p = h2f(u2.y); a2 += p.x; a3 += p.y;
        p = h2f(u3.x); a0 += p.x; a1 += p.y;  p = h2f(u3.y); a2 += p.x; a3 += p.y;
    }
    for (; j < end; j += 2) {
        int jj = j + half;
        float m = (jj < end) ? 1.f : 0.f;
        int s = srcs[(jj < end) ? jj : (end - 1)];
        uint2 u = xh4[(size_t)s * 32 + col];
        float2 p;
        p = h2f(u.x); a0 += m * p.x; a1 += m * p.y;
        p = h2f(u.y); a2 += m * p.x; a3 += m * p.y;
    }
    a0 += __shfl_xor(a0, 32); a1 += __shfl_xor(a1, 32);
    a2 += __shfl_xor(a2, 32); a3 += __shfl_xor(a3, 32);
    if (half == 0) {
        uint2 o; o.x = f2h(a0, a1); o.y = f2h(a2, a3);
        aggh4[(size_t)w * 32 + col] = o;
    }
}

__global__ __launch_bounds__(256) void pull_add_h64(const uint2* __restrict__ hr4,
                                                    const int* __restrict__ row_ptr,
                                                    const int* __restrict__ srcs,
                                                    float* __restrict__ out, int N)
{
    const int w   = (blockIdx.x * 256 + threadIdx.x) >> 6;
    const int l   = threadIdx.x & 63;
    const int q   = l >> 4;
    const int col = l & 15;
    if (w >= N) return;
    const int beg = row_ptr[w], end = row_ptr[w + 1];
    float a0 = 0.f, a1 = 0.f, a2 = 0.f, a3 = 0.f;
    int j = beg;
    for (; j + 7 < end; j += 8) {
        int s0 = srcs[j + q], s1 = srcs[j + 4 + q];
        uint2 u0 = hr4[(size_t)s0 * 16 + col];
        uint2 u1 = hr4[(size_t)s1 * 16 + col];
        float2 p;
        p = h2f(u0.x); a0 += p.x; a1 += p.y;  p = h2f(u0.y); a2 += p.x; a3 += p.y;
        p = h2f(u1.x); a0 += p.x; a1 += p.y;  p = h2f(u1.y); a2 += p.x; a3 += p.y;
    }
    for (; j < end; j += 4) {
        int jj = j + q;
        float m = (jj < end) ? 1.f : 0.f;
        int s = srcs[(jj < end) ? jj : (end - 1)];
        uint2 u = hr4[(size_t)s * 16 + col];
        float2 p;
        p = h2f(u.x); a0 += m * p.x; a1 += m * p.y;
        p = h2f(u.y); a2 += m * p.x; a3 += m * p.y;
    }
    a0 += __shfl_xor(a0, 16); a1 += __shfl_xor(a1, 16);
    a2 += __shfl_xor(a2, 16); a3 += __shfl_xor(a3, 16);
    a0 += __shfl_xor(a0, 32); a1 += __shfl_xor(a1, 32);
    a2 += __shfl_xor(a2, 32); a3 += __shfl_xor(a3, 32);
    if (q == 0) {
        f4* po = (f4*)out + (size_t)w * 16 + col;
        f4 cur = *po;
        cur[0] += a0; cur[1] += a1; cur[2] += a2; cur[3] += a3;
        *po = cur;
    }
}

// ----------------------- FUSED MFMA GEMM v3 (weights in LDS) ----------------
// 256 threads = 4 waves; block = 128 rows; wave = 32 rows x 128 cols.
// LDS: lw[49152] = all weights, 16B-slot XOR swizzle (slot ^= row&15) ->
// conflict-free ds_read_b128; hs[4][32*128] = per-wave h tile (R14 swizzle).
// A-frags prefetched to regs BEFORE staging (latency hides under it).
__global__ __launch_bounds__(256) void mfma_fused(
    const _Float16* __restrict__ aggh, const _Float16* __restrict__ xh,
    const _Float16* __restrict__ wb,   // wr1h@0, wq1h@16384, wr2h@32768, wq2h@40960
    const float* __restrict__ b1, const float* __restrict__ b2,
    _Float16* __restrict__ hrh, float* __restrict__ outp, int N)
{
    __shared__ _Float16 smem[49152 + 4 * 32 * 128];   // 96 KB + 32 KB = 128 KB
    _Float16* lw = smem;
    const int tid = threadIdx.x;
    const int wv = tid >> 6;
    const int l  = tid & 63;
    const int lr = l & 15;
    const int kg = l >> 4;
    const int base = blockIdx.x * 128 + wv * 32;
    const int r0 = min(base + lr,      N - 1);
    const int r1 = min(base + 16 + lr, N - 1);
    _Float16* hb = smem + 49152 + wv * (32 * 128);

    // ---- prefetch all 16 A-frags (aggh/xh x 2 rows x 4 chunks) ----
    h8 afr0[8], afr1[8];
#pragma unroll
    for (int c = 0; c < 4; ++c) {
        const int k0 = c * 32 + kg * 8;
        afr0[c]     = *(const h8*)(aggh + (size_t)r0 * 128 + k0);
        afr0[c + 4] = *(const h8*)(xh   + (size_t)r0 * 128 + k0);
        afr1[c]     = *(const h8*)(aggh + (size_t)r1 * 128 + k0);
        afr1[c + 4] = *(const h8*)(xh   + (size_t)r1 * 128 + k0);
    }

    // ---- stage weights global->LDS, swizzled: 16B chunk g -> slot^=(row&15)
#pragma unroll
    for (int it = 0; it < 24; ++it) {
        int g = tid + it * 256;                       // 0..6143
        int d = (g & ~15) | ((g ^ (g >> 4)) & 15);
        *(h8*)&lw[d * 8] = *(const h8*)(wb + (size_t)g * 8);
    }
    __syncthreads();

    // ---- layer 1: K=256 dual, B from LDS ----
    f4 acc0[8], acc1[8];
#pragma unroll
    for (int n = 0; n < 8; ++n) { acc0[n] = 0.f; acc1[n] = 0.f; }
#pragma unroll
    for (int kk = 0; kk < 8; ++kk) {
        const int R = (kk < 4) ? 0 : 16384;
        const int sl = ((kk & 3) * 4 + kg) ^ lr;      // swizzled 16B slot
#pragma unroll
        for (int n = 0; n < 8; ++n) {
            h8 bf = *(const h8*)&lw[R + (n * 16 + lr) * 128 + (sl << 3)];
            acc0[n] = __builtin_amdgcn_mfma_f32_16x16x32_f16(afr0[kk], bf, acc0[n], 0, 0, 0);
            acc1[n] = __builtin_amdgcn_mfma_f32_16x16x32_f16(afr1[kk], bf, acc1[n], 0, 0, 0);
        }
    }

    // ---- relu+bias -> swizzled per-wave h tile ----
    const int ro = kg * 4;
#pragma unroll
    for (int n = 0; n < 8; ++n) {
        const int col = n * 16 + lr;
        const float bias = b1[col];
#pragma unroll
        for (int j = 0; j < 4; ++j) {
            const int row0 = ro + j;
            const int row1 = 16 + ro + j;
            hb[row0 * 128 + (col ^ ((row0 & 7) << 3))] =
                (_Float16)fmaxf(acc0[n][j] + bias, 0.f);
            hb[row1 * 128 + (col ^ ((row1 & 7) << 3))] =
                (_Float16)fmaxf(acc1[n][j] + bias, 0.f);
        }
    }
    __syncthreads();

    // ---- layer 2: K=128, A from h tile, B from LDS ----
    f4 c20[8], c21[8];
#pragma unroll
    for (int n = 0; n < 8; ++n) { c20[n] = 0.f; c21[n] = 0.f; }
#pragma unroll
    for (int kk = 0; kk < 4; ++kk) {
        const int k0 = kk * 32 + kg * 8;
        const int swz = (lr & 7) << 3;
        h8 a0 = *(const h8*)&hb[lr * 128 + (k0 ^ swz)];
        h8 a1 = *(const h8*)&hb[(16 + lr) * 128 + (k0 ^ swz)];
        const int sl = (kk * 4 + kg) ^ lr;
#pragma unroll
        for (int n = 0; n < 8; ++n) {
            const int R2 = (n < 4) ? 32768 : 40960;
            h8 bf = *(const h8*)&lw[R2 + ((n & 3) * 16 + lr) * 128 + (sl << 3)];
            c20[n] = __builtin_amdgcn_mfma_f32_16x16x32_f16(a0, bf, c20[n], 0, 0, 0);
            c21[n] = __builtin_amdgcn_mfma_f32_16x16x32_f16(a1, bf, c21[n], 0, 0, 0);
        }
    }

    // ---- epilogue: cols 0..63 -> hr(f16), 64..127 -> out(f32)+b2 ----
#pragma unroll
    for (int n = 0; n < 8; ++n) {
        const int col = n * 16 + lr;
#pragma unroll
        for (int j = 0; j < 4; ++j) {
            int ra = base + ro + j;
            int rb = base + 16 + ro + j;
            if (n < 4) {
                if (ra < N) hrh[(size_t)ra * 64 + col] = (_Float16)c20[n][j];
                if (rb < N) hrh[(size_t)rb * 64 + col] = (_Float16)c21[n][j];
            } else {
                const float bias = b2[col - 64];
                if (ra < N) outp[(size_t)ra * 64 + (col - 64)] = c20[n][j] + bias;
                if (rb < N) outp[(size_t)rb * 64 + (col - 64)] = c21[n][j] + bias;
            }
        }
    }
}

extern "C" void kernel_launch(void* const* d_in, const int* in_sizes, int n_in,
                              void* d_out, int out_size, void* d_ws, size_t ws_size,
                              hipStream_t stream)
{
    const float* x       = (const float*)d_in[0];
    const int*   ei      = (const int*)d_in[1];
    const float* w_rel1  = (const float*)d_in[2];
    const float* b_rel1  = (const float*)d_in[3];
    const float* w_root1 = (const float*)d_in[4];
    const float* w_rel2  = (const float*)d_in[5];
    const float* b_rel2  = (const float*)d_in[6];
    const float* w_root2 = (const float*)d_in[7];
    float* out = (float*)d_out;

    const int N = in_sizes[0] / 128;
    const int E = in_sizes[1] / 2;
    const int* src = ei;        // edge_index[0]
    const int* dst = ei + E;    // edge_index[1]

    // workspace (~67 MB):
    //   xh [N*128 h] | aggh [N*128 h] (hrh aliases) | wbuf [49152 h]
    //   | srcs [E] | coarse [E u32] | mat [nblk*NB] | tot [NB] | bb [NB+1]
    //   | row_ptr [N+1]
    _Float16* xh    = (_Float16*)d_ws;
    _Float16* aggh  = xh + (size_t)N * 128;
    _Float16* hrh   = aggh;                         // alias: aggh dead after gemm
    _Float16* wbuf  = aggh + (size_t)N * 128;
    int*      srcs    = (int*)(wbuf + 49152);
    unsigned* coarse  = (unsigned*)(srcs + E);
    const int nblk    = (E + EPB - 1) / EPB;        // <= 512 (E <= 2M)
    int*      mat     = (int*)(coarse + E);         // nblk*NB
    int*      tot     = mat + (size_t)nblk * NB;    // NB
    int*      bb      = tot + NB;                   // NB+1
    int*      row_ptr = bb + (NB + 1);              // N+1

    // ---- f16 staging ----
    wcast<<<(49152 + 255) / 256, 256, 0, stream>>>(w_rel1, w_root1, w_rel2, w_root2, wbuf);
    xcast<<<(N * 128 / 8 + 255) / 256, 256, 0, stream>>>(x, xh, (long)N * 128);

    // ---- CSR build: atomic-free 2-level counting sort ----
    s1_hist   <<<nblk, 256, 0, stream>>>(dst, mat, E);
    s2_colscan<<<NB, 512, 0, stream>>>(mat, tot, nblk);
    s2b_base  <<<1, NB, 0, stream>>>(tot, bb, row_ptr, N, E);
    s3_scatter<<<nblk, 256, 0, stream>>>(src, dst, mat, bb, coarse, E);
    s4_fine   <<<NB, 256, 0, stream>>>(coarse, bb, row_ptr, srcs, N);

    // 1. aggh = pull-sum xh
    pull_h128<<<(N * 64 + 255) / 256, 256, 0, stream>>>(
        (const uint2*)xh, row_ptr, srcs, (uint2*)aggh, N);

    // 2. fused GEMMs: hr(f16) = relu(...)@Wr2^T ; out = relu(...)@Wq2^T + b2
    mfma_fused<<<(N + 127) / 128, 256, 0, stream>>>(
        aggh, xh, wbuf, b_rel1, b_rel2, hrh, out, N);

    // 3. out += pull-sum hr
    pull_add_h64<<<(N * 64 + 255) / 256, 256, 0, stream>>>(
        (const uint2*)hrh, row_ptr, srcs, out, N);
}

// Round 17
// 206.476 us; speedup vs baseline: 1.3442x; 1.0953x over previous
//
#include <hip/hip_runtime.h>

// GraphConv x2, CSR-pull + PERSISTENT FUSED f16 MFMA GEMMs (R17):
//   wcast/xcast -> f16 staging (row-major)
//   CSR build: atomic-free 2-level counting sort (R11)
//   pull_h128: aggh = sum xh[srcs]          (R9, 62us = gather floor)
//   mfma_fused v4: PERSISTENT 256 blocks x 512 threads (8 waves x 16 rows);
//     96KB swizzled weights staged ONCE, then barrier-free tile loop
//     (per-wave-private h tiles); 2 waves/SIMD hide A-load + LDS latency.
//   pull_add_h64: out += sum hr[srcs]       (R9)
//
// R17 rationale: R16's fused = ~54us (242-226 delta vs R14's 70): 1 block/CU
// x 4 waves = 1 wave/SIMD exposed every latency, and 96KB staging was repaid
// 3.05x (782 blocks / 256 CUs). v4: persistent blocks stage weights once;
// 8 waves -> 2/SIMD; h-tile is per-wave private so the tile loop has NO
// barriers. LDS-pipe model ~12us + MFMA ~3us -> predict 18-25us.

typedef float f4 __attribute__((ext_vector_type(4)));
typedef _Float16 h8 __attribute__((ext_vector_type(8)));
typedef _Float16 h2 __attribute__((ext_vector_type(2)));

#define NB   1024    // coarse buckets (dst>>7); requires N <= 131072
#define EPB  4096    // edges per block in s1/s3; nblk = ceil(E/EPB) <= 512

__device__ __forceinline__ float2 h2f(unsigned u) {
    h2 p = __builtin_bit_cast(h2, u);
    float2 r; r.x = (float)p[0]; r.y = (float)p[1];
    return r;
}
__device__ __forceinline__ unsigned f2h(float a, float b) {
    h2 p; p[0] = (_Float16)a; p[1] = (_Float16)b;
    return __builtin_bit_cast(unsigned, p);
}

// ---------------------------- casts ----------------------------------------
// wbuf layout (halves): wr1h @0 [128x128] | wq1h @16384 | wr2h @32768 [64x128]
// | wq2h @40960  (total 49152)
__global__ void wcast(const float* __restrict__ wr1, const float* __restrict__ wq1,
                      const float* __restrict__ wr2, const float* __restrict__ wq2,
                      _Float16* __restrict__ wb)
{
    int i = blockIdx.x * 256 + threadIdx.x;
    if (i < 16384)      wb[i] = (_Float16)wr1[i];
    else if (i < 32768) wb[i] = (_Float16)wq1[i - 16384];
    else if (i < 40960) wb[i] = (_Float16)wr2[i - 32768];
    else if (i < 49152) wb[i] = (_Float16)wq2[i - 40960];
}

__global__ void xcast(const float* __restrict__ x, _Float16* __restrict__ xh,
                      long n)   // n = N*128, multiple of 8
{
    long i = (long)(blockIdx.x * 256 + threadIdx.x) * 8;
    if (i >= n) return;
    f4 a = *(const f4*)(x + i);
    f4 b = *(const f4*)(x + i + 4);
    h8 o;
    o[0] = (_Float16)a[0]; o[1] = (_Float16)a[1];
    o[2] = (_Float16)a[2]; o[3] = (_Float16)a[3];
    o[4] = (_Float16)b[0]; o[5] = (_Float16)b[1];
    o[6] = (_Float16)b[2]; o[7] = (_Float16)b[3];
    *(h8*)(xh + i) = o;
}

// ------------------ CSR build: atomic-free counting sort --------------------
__global__ __launch_bounds__(256) void s1_hist(const int* __restrict__ dst,
                                               int* __restrict__ mat, int E)
{
    __shared__ int hist[NB];
    const int tid = threadIdx.x;
    for (int i = tid; i < NB; i += 256) hist[i] = 0;
    __syncthreads();
    const int e0 = blockIdx.x * EPB;
#pragma unroll
    for (int it = 0; it < EPB / 256; ++it) {
        int e = e0 + it * 256 + tid;
        if (e < E) atomicAdd(&hist[dst[e] >> 7], 1);
    }
    __syncthreads();
    int* row = mat + (size_t)blockIdx.x * NB;
    for (int i = tid; i < NB; i += 256) row[i] = hist[i];
}

__global__ __launch_bounds__(512) void s2_colscan(int* __restrict__ mat,
                                                  int* __restrict__ tot, int nblk)
{
    __shared__ int ts[512];
    const int tid = threadIdx.x;
    const int b = blockIdx.x;
    int v = (tid < nblk) ? mat[(size_t)tid * NB + b] : 0;
    ts[tid] = v;
    __syncthreads();
#pragma unroll
    for (int off = 1; off < 512; off <<= 1) {
        int add = (tid >= off) ? ts[tid - off] : 0;
        __syncthreads();
        ts[tid] += add;
        __syncthreads();
    }
    if (tid < nblk) mat[(size_t)tid * NB + b] = ts[tid] - v;
    if (tid == 511) tot[b] = ts[511];
}

__global__ __launch_bounds__(NB) void s2b_base(const int* __restrict__ tot,
                                               int* __restrict__ bb,
                                               int* __restrict__ row_ptr,
                                               int N, int E)
{
    __shared__ int ts[NB];
    const int tid = threadIdx.x;
    int v = tot[tid];
    ts[tid] = v;
    __syncthreads();
#pragma unroll
    for (int off = 1; off < NB; off <<= 1) {
        int add = (tid >= off) ? ts[tid - off] : 0;
        __syncthreads();
        ts[tid] += add;
        __syncthreads();
    }
    bb[tid] = ts[tid] - v;
    if (tid == NB - 1) { bb[NB] = ts[NB - 1]; row_ptr[N] = E; }
}

__global__ __launch_bounds__(256) void s3_scatter(const int* __restrict__ src,
                                                  const int* __restrict__ dst,
                                                  const int* __restrict__ mat,
                                                  const int* __restrict__ bb,
                                                  unsigned* __restrict__ coarse, int E)
{
    __shared__ int cur[NB];
    const int tid = threadIdx.x;
    const int* mrow = mat + (size_t)blockIdx.x * NB;
    for (int i = tid; i < NB; i += 256) cur[i] = bb[i] + mrow[i];
    __syncthreads();
    const int e0 = blockIdx.x * EPB;
#pragma unroll
    for (int it = 0; it < EPB / 256; ++it) {
        int e = e0 + it * 256 + tid;
        if (e < E) {
            int d = dst[e];
            int p = atomicAdd(&cur[d >> 7], 1);
            coarse[p] = ((unsigned)src[e] << 7) | (unsigned)(d & 127);
        }
    }
}

__global__ __launch_bounds__(256) void s4_fine(const unsigned* __restrict__ coarse,
                                               const int* __restrict__ bb,
                                               int* __restrict__ row_ptr,
                                               int* __restrict__ srcs, int N)
{
    __shared__ int fcnt[128];
    __shared__ int fs[128];
    __shared__ int cur[128];
    const int tid = threadIdx.x;
    const int b = blockIdx.x;
    const int seg0 = bb[b], seg1 = bb[b + 1];
    if (tid < 128) fcnt[tid] = 0;
    __syncthreads();
    for (int p = seg0 + tid; p < seg1; p += 256)
        atomicAdd(&fcnt[coarse[p] & 127u], 1);
    __syncthreads();
    if (tid < 128) fs[tid] = fcnt[tid];
    __syncthreads();
#pragma unroll
    for (int off = 1; off < 128; off <<= 1) {
        int add = 0;
        if (tid < 128 && tid >= off) add = fs[tid - off];
        __syncthreads();
        if (tid < 128) fs[tid] += add;
        __syncthreads();
    }
    if (tid < 128) {
        int excl = fs[tid] - fcnt[tid];
        cur[tid] = seg0 + excl;
        int d = b * 128 + tid;
        if (d < N) row_ptr[d] = seg0 + excl;
    }
    __syncthreads();
    for (int p = seg0 + tid; p < seg1; p += 256) {
        unsigned v = coarse[p];
        int q = atomicAdd(&cur[v & 127u], 1);
        srcs[q] = (int)(v >> 7);
    }
}

// --------------------------- pull kernels (R9 versions) ---------------------
__global__ __launch_bounds__(256) void pull_h128(const uint2* __restrict__ xh4,
                                                 const int* __restrict__ row_ptr,
                                                 const int* __restrict__ srcs,
                                                 uint2* __restrict__ aggh4, int N)
{
    const int w    = (blockIdx.x * 256 + threadIdx.x) >> 6;
    const int l    = threadIdx.x & 63;
    const int half = l >> 5;
    const int col  = l & 31;
    if (w >= N) return;
    const int beg = row_ptr[w], end = row_ptr[w + 1];
    float a0 = 0.f, a1 = 0.f, a2 = 0.f, a3 = 0.f;
    int j = beg;
    for (; j + 7 < end; j += 8) {
        int s0 = srcs[j + 0 + half], s1 = srcs[j + 2 + half];
        int s2 = srcs[j + 4 + half], s3 = srcs[j + 6 + half];
        uint2 u0 = xh4[(size_t)s0 * 32 + col];
        uint2 u1 = xh4[(size_t)s1 * 32 + col];
        uint2 u2 = xh4[(size_t)s2 * 32 + col];
        uint2 u3 = xh4[(size_t)s3 * 32 + col];
        float2 p;
        p = h2f(u0.x); a0 += p.x; a1 += p.y;  p = h2f(u0.y); a2 += p.x; a3 += p.y;
        p = h2f(u1.x); a0 += p.x; a1 += p.y;  p = h2f(u1.y); a2 += p.x; a3 += p.y;
        p = h2f(u2.x); a0 += p.x; a1 += p.y;  p = h2f(u2.y); a2 += p.x; a3 += p.y;
        p = h2f(u3.x); a0 += p.x; a1 += p.y;  p = h2f(u3.y); a2 += p.x; a3 += p.y;
    }
    for (; j < end; j += 2) {
        int jj = j + half;
        float m = (jj < end) ? 1.f : 0.f;
        int s = srcs[(jj < end) ? jj : (end - 1)];
        uint2 u = xh4[(size_t)s * 32 + col];
        float2 p;
        p = h2f(u.x); a0 += m * p.x; a1 += m * p.y;
        p = h2f(u.y); a2 += m * p.x; a3 += m * p.y;
    }
    a0 += __shfl_xor(a0, 32); a1 += __shfl_xor(a1, 32);
    a2 += __shfl_xor(a2, 32); a3 += __shfl_xor(a3, 32);
    if (half == 0) {
        uint2 o; o.x = f2h(a0, a1); o.y = f2h(a2, a3);
        aggh4[(size_t)w * 32 + col] = o;
    }
}

__global__ __launch_bounds__(256) void pull_add_h64(const uint2* __restrict__ hr4,
                                                    const int* __restrict__ row_ptr,
                                                    const int* __restrict__ srcs,
                                                    float* __restrict__ out, int N)
{
    const int w   = (blockIdx.x * 256 + threadIdx.x) >> 6;
    const int l   = threadIdx.x & 63;
    const int q   = l >> 4;
    const int col = l & 15;
    if (w >= N) return;
    const int beg = row_ptr[w], end = row_ptr[w + 1];
    float a0 = 0.f, a1 = 0.f, a2 = 0.f, a3 = 0.f;
    int j = beg;
    for (; j + 7 < end; j += 8) {
        int s0 = srcs[j + q], s1 = srcs[j + 4 + q];
        uint2 u0 = hr4[(size_t)s0 * 16 + col];
        uint2 u1 = hr4[(size_t)s1 * 16 + col];
        float2 p;
        p = h2f(u0.x); a0 += p.x; a1 += p.y;  p = h2f(u0.y); a2 += p.x; a3 += p.y;
        p = h2f(u1.x); a0 += p.x; a1 += p.y;  p = h2f(u1.y); a2 += p.x; a3 += p.y;
    }
    for (; j < end; j += 4) {
        int jj = j + q;
        float m = (jj < end) ? 1.f : 0.f;
        int s = srcs[(jj < end) ? jj : (end - 1)];
        uint2 u = hr4[(size_t)s * 16 + col];
        float2 p;
        p = h2f(u.x); a0 += m * p.x; a1 += m * p.y;
        p = h2f(u.y); a2 += m * p.x; a3 += m * p.y;
    }
    a0 += __shfl_xor(a0, 16); a1 += __shfl_xor(a1, 16);
    a2 += __shfl_xor(a2, 16); a3 += __shfl_xor(a3, 16);
    a0 += __shfl_xor(a0, 32); a1 += __shfl_xor(a1, 32);
    a2 += __shfl_xor(a2, 32); a3 += __shfl_xor(a3, 32);
    if (q == 0) {
        f4* po = (f4*)out + (size_t)w * 16 + col;
        f4 cur = *po;
        cur[0] += a0; cur[1] += a1; cur[2] += a2; cur[3] += a3;
        *po = cur;
    }
}

// ------------- PERSISTENT FUSED MFMA GEMM v4 (weights staged once) ----------
// 256 blocks x 512 threads (8 waves x 16 rows = 128 rows/tile). Weights
// (96KB, 16B-slot XOR swizzle slot^=(row&15)) staged once; tile loop is
// BARRIER-FREE (h tiles are per-wave private).
__global__ __launch_bounds__(512) void mfma_fused(
    const _Float16* __restrict__ aggh, const _Float16* __restrict__ xh,
    const _Float16* __restrict__ wb,   // wr1h@0, wq1h@16384, wr2h@32768, wq2h@40960
    const float* __restrict__ b1, const float* __restrict__ b2,
    _Float16* __restrict__ hrh, float* __restrict__ outp, int N)
{
    __shared__ _Float16 smem[49152 + 8 * 16 * 128];   // 96 KB + 32 KB = 128 KB
    _Float16* lw = smem;
    const int tid = threadIdx.x;
    const int wv = tid >> 6;
    const int l  = tid & 63;
    const int lr = l & 15;
    const int kg = l >> 4;
    _Float16* hb = smem + 49152 + wv * (16 * 128);

    // ---- stage weights global->LDS once: 16B chunk g -> slot ^= (row&15) ----
#pragma unroll
    for (int it = 0; it < 12; ++it) {
        int g = tid + it * 512;                       // 0..6143
        int d = (g & ~15) | ((g ^ (g >> 4)) & 15);
        *(h8*)&lw[d * 8] = *(const h8*)(wb + (size_t)g * 8);
    }
    __syncthreads();

    const int ntiles = (N + 127) / 128;
    for (int t = blockIdx.x; t < ntiles; t += gridDim.x) {
        const int base = t * 128 + wv * 16;
        const int r0 = min(base + lr, N - 1);

        // prefetch 8 A-frags (4 aggh + 4 xh), independent loads
        h8 afr[8];
#pragma unroll
        for (int c = 0; c < 4; ++c) {
            const int k0 = c * 32 + kg * 8;
            afr[c]     = *(const h8*)(aggh + (size_t)r0 * 128 + k0);
            afr[c + 4] = *(const h8*)(xh   + (size_t)r0 * 128 + k0);
        }

        // layer 1: K=256 dual, B from LDS
        f4 acc[8];
#pragma unroll
        for (int n = 0; n < 8; ++n) acc[n] = 0.f;
#pragma unroll
        for (int kk = 0; kk < 8; ++kk) {
            const int R = (kk < 4) ? 0 : 16384;
            const int sl = ((kk & 3) * 4 + kg) ^ lr;  // swizzled 16B slot
#pragma unroll
            for (int n = 0; n < 8; ++n) {
                h8 bf = *(const h8*)&lw[R + (n * 16 + lr) * 128 + (sl << 3)];
                acc[n] = __builtin_amdgcn_mfma_f32_16x16x32_f16(afr[kk], bf, acc[n], 0, 0, 0);
            }
        }

        // relu+bias -> per-wave swizzled h tile (no barrier: wave-private)
        const int ro = kg * 4;
#pragma unroll
        for (int n = 0; n < 8; ++n) {
            const int col = n * 16 + lr;
            const float bias = b1[col];
#pragma unroll
            for (int j = 0; j < 4; ++j) {
                const int row = ro + j;
                hb[row * 128 + (col ^ ((row & 7) << 3))] =
                    (_Float16)fmaxf(acc[n][j] + bias, 0.f);
            }
        }

        // layer 2: K=128, A from own h tile, B from LDS
        f4 acc2[8];
#pragma unroll
        for (int n = 0; n < 8; ++n) acc2[n] = 0.f;
#pragma unroll
        for (int kk = 0; kk < 4; ++kk) {
            const int k0 = kk * 32 + kg * 8;
            const int swz = (lr & 7) << 3;
            h8 a0 = *(const h8*)&hb[lr * 128 + (k0 ^ swz)];
            const int sl = (kk * 4 + kg) ^ lr;
#pragma unroll
            for (int n = 0; n < 8; ++n) {
                const int R2 = (n < 4) ? 32768 : 40960;
                h8 bf = *(const h8*)&lw[R2 + ((n & 3) * 16 + lr) * 128 + (sl << 3)];
                acc2[n] = __builtin_amdgcn_mfma_f32_16x16x32_f16(a0, bf, acc2[n], 0, 0, 0);
            }
        }

        // epilogue: cols 0..63 -> hr(f16), 64..127 -> out(f32)+b2
#pragma unroll
        for (int n = 0; n < 8; ++n) {
            const int col = n * 16 + lr;
#pragma unroll
            for (int j = 0; j < 4; ++j) {
                int r = base + ro + j;
                if (r < N) {
                    if (n < 4) {
                        hrh[(size_t)r * 64 + col] = (_Float16)acc2[n][j];
                    } else {
                        outp[(size_t)r * 64 + (col - 64)] = acc2[n][j] + b2[col - 64];
                    }
                }
            }
        }
    }
}

extern "C" void kernel_launch(void* const* d_in, const int* in_sizes, int n_in,
                              void* d_out, int out_size, void* d_ws, size_t ws_size,
                              hipStream_t stream)
{
    const float* x       = (const float*)d_in[0];
    const int*   ei      = (const int*)d_in[1];
    const float* w_rel1  = (const float*)d_in[2];
    const float* b_rel1  = (const float*)d_in[3];
    const float* w_root1 = (const float*)d_in[4];
    const float* w_rel2  = (const float*)d_in[5];
    const float* b_rel2  = (const float*)d_in[6];
    const float* w_root2 = (const float*)d_in[7];
    float* out = (float*)d_out;

    const int N = in_sizes[0] / 128;
    const int E = in_sizes[1] / 2;
    const int* src = ei;        // edge_index[0]
    const int* dst = ei + E;    // edge_index[1]

    // workspace (~67 MB):
    //   xh [N*128 h] | aggh [N*128 h] (hrh aliases) | wbuf [49152 h]
    //   | srcs [E] | coarse [E u32] | mat [nblk*NB] | tot [NB] | bb [NB+1]
    //   | row_ptr [N+1]
    _Float16* xh    = (_Float16*)d_ws;
    _Float16* aggh  = xh + (size_t)N * 128;
    _Float16* hrh   = aggh;                         // alias: aggh dead after gemm
    _Float16* wbuf  = aggh + (size_t)N * 128;
    int*      srcs    = (int*)(wbuf + 49152);
    unsigned* coarse  = (unsigned*)(srcs + E);
    const int nblk    = (E + EPB - 1) / EPB;        // <= 512 (E <= 2M)
    int*      mat     = (int*)(coarse + E);         // nblk*NB
    int*      tot     = mat + (size_t)nblk * NB;    // NB
    int*      bb      = tot + NB;                   // NB+1
    int*      row_ptr = bb + (NB + 1);              // N+1

    // ---- f16 staging ----
    wcast<<<(49152 + 255) / 256, 256, 0, stream>>>(w_rel1, w_root1, w_rel2, w_root2, wbuf);
    xcast<<<(N * 128 / 8 + 255) / 256, 256, 0, stream>>>(x, xh, (long)N * 128);

    // ---- CSR build: atomic-free 2-level counting sort ----
    s1_hist   <<<nblk, 256, 0, stream>>>(dst, mat, E);
    s2_colscan<<<NB, 512, 0, stream>>>(mat, tot, nblk);
    s2b_base  <<<1, NB, 0, stream>>>(tot, bb, row_ptr, N, E);
    s3_scatter<<<nblk, 256, 0, stream>>>(src, dst, mat, bb, coarse, E);
    s4_fine   <<<NB, 256, 0, stream>>>(coarse, bb, row_ptr, srcs, N);

    // 1. aggh = pull-sum xh
    pull_h128<<<(N * 64 + 255) / 256, 256, 0, stream>>>(
        (const uint2*)xh, row_ptr, srcs, (uint2*)aggh, N);

    // 2. persistent fused GEMMs
    mfma_fused<<<256, 512, 0, stream>>>(
        aggh, xh, wbuf, b_rel1, b_rel2, hrh, out, N);

    // 3. out += pull-sum hr
    pull_add_h64<<<(N * 64 + 255) / 256, 256, 0, stream>>>(
        (const uint2*)hrh, row_ptr, srcs, out, N);
}

// Round 18
// 205.853 us; speedup vs baseline: 1.3482x; 1.0030x over previous
//
#include <hip/hip_runtime.h>

// GraphConv x2, CSR-pull + PERSISTENT FUSED f16 MFMA GEMMs (R18):
//   prep_fused: s1 coarse hist (LDS-atomic, latency-bound) + xcast + wcast
//               (BW-bound) fused into one kernel -> pipes overlap
//   CSR build: s2/s2b/s3/s4 (R11, unchanged)
//   pull_h128 / pull_add_h64: R9 versions (62/31us = line-fetch floor,
//               6.6 TB/s delivered — confirmed saturated 5 rounds running)
//   mfma_fused v5: R17 persistent structure + A-frag DOUBLE BUFFER across
//               the barrier-free tile loop (next tile's loads hide under
//               current tile's MFMAs)
//
// R18 rationale: top-5 is all pull_h128 at its measured fabric floor.
// Remaining costs: casts ~14us serialized (now overlapped into hist),
// fused gemm ~34us (A-load latency at 2 waves/SIMD -> cross-tile prefetch).

typedef float f4 __attribute__((ext_vector_type(4)));
typedef _Float16 h8 __attribute__((ext_vector_type(8)));
typedef _Float16 h2 __attribute__((ext_vector_type(2)));

#define NB   1024    // coarse buckets (dst>>7); requires N <= 131072
#define EPB  4096    // edges per block in s1/s3; nblk = ceil(E/EPB) <= 512

__device__ __forceinline__ float2 h2f(unsigned u) {
    h2 p = __builtin_bit_cast(h2, u);
    float2 r; r.x = (float)p[0]; r.y = (float)p[1];
    return r;
}
__device__ __forceinline__ unsigned f2h(float a, float b) {
    h2 p; p[0] = (_Float16)a; p[1] = (_Float16)b;
    return __builtin_bit_cast(unsigned, p);
}

// ---------------- prep: coarse hist + xcast + wcast in one kernel -----------
// wbuf layout (halves): wr1h @0 [128x128] | wq1h @16384 | wr2h @32768 [64x128]
// | wq2h @40960  (total 49152 = 6144 h8-chunks)
__global__ __launch_bounds__(256) void prep_fused(
    const int* __restrict__ dst, int* __restrict__ mat,
    const float* __restrict__ x, _Float16* __restrict__ xh,
    const float* __restrict__ wr1, const float* __restrict__ wq1,
    const float* __restrict__ wr2, const float* __restrict__ wq2,
    _Float16* __restrict__ wb, int E, long nxchunks)
{
    __shared__ int hist[NB];
    const int tid = threadIdx.x;
    for (int i = tid; i < NB; i += 256) hist[i] = 0;
    __syncthreads();
    // --- coarse histogram (LDS atomics; latency-bound) ---
    const int e0 = blockIdx.x * EPB;
#pragma unroll
    for (int it = 0; it < EPB / 256; ++it) {
        int e = e0 + it * 256 + tid;
        if (e < E) atomicAdd(&hist[dst[e] >> 7], 1);
    }
    // --- xcast slice (BW-bound; overlaps the atomics' latency) ---
    const long stride = (long)gridDim.x * 256;
    for (long c = (long)blockIdx.x * 256 + tid; c < nxchunks; c += stride) {
        const float* p = x + c * 8;
        f4 a = *(const f4*)p;
        f4 b = *(const f4*)(p + 4);
        h8 o;
        o[0] = (_Float16)a[0]; o[1] = (_Float16)a[1];
        o[2] = (_Float16)a[2]; o[3] = (_Float16)a[3];
        o[4] = (_Float16)b[0]; o[5] = (_Float16)b[1];
        o[6] = (_Float16)b[2]; o[7] = (_Float16)b[3];
        *(h8*)(xh + c * 8) = o;
    }
    // --- wcast: blocks 0..23, one h8-chunk per thread ---
    if (blockIdx.x < 24) {
        int i = (blockIdx.x * 256 + tid) * 8;
#pragma unroll
        for (int k = 0; k < 8; ++k) {
            int j = i + k;
            _Float16 v;
            if (j < 16384)      v = (_Float16)wr1[j];
            else if (j < 32768) v = (_Float16)wq1[j - 16384];
            else if (j < 40960) v = (_Float16)wr2[j - 32768];
            else                v = (_Float16)wq2[j - 40960];
            wb[j] = v;
        }
    }
    __syncthreads();
    int* row = mat + (size_t)blockIdx.x * NB;
    for (int i = tid; i < NB; i += 256) row[i] = hist[i];
}

// ------------------ CSR build: atomic-free counting sort --------------------
__global__ __launch_bounds__(512) void s2_colscan(int* __restrict__ mat,
                                                  int* __restrict__ tot, int nblk)
{
    __shared__ int ts[512];
    const int tid = threadIdx.x;
    const int b = blockIdx.x;
    int v = (tid < nblk) ? mat[(size_t)tid * NB + b] : 0;
    ts[tid] = v;
    __syncthreads();
#pragma unroll
    for (int off = 1; off < 512; off <<= 1) {
        int add = (tid >= off) ? ts[tid - off] : 0;
        __syncthreads();
        ts[tid] += add;
        __syncthreads();
    }
    if (tid < nblk) mat[(size_t)tid * NB + b] = ts[tid] - v;
    if (tid == 511) tot[b] = ts[511];
}

__global__ __launch_bounds__(NB) void s2b_base(const int* __restrict__ tot,
                                               int* __restrict__ bb,
                                               int* __restrict__ row_ptr,
                                               int N, int E)
{
    __shared__ int ts[NB];
    const int tid = threadIdx.x;
    int v = tot[tid];
    ts[tid] = v;
    __syncthreads();
#pragma unroll
    for (int off = 1; off < NB; off <<= 1) {
        int add = (tid >= off) ? ts[tid - off] : 0;
        __syncthreads();
        ts[tid] += add;
        __syncthreads();
    }
    bb[tid] = ts[tid] - v;
    if (tid == NB - 1) { bb[NB] = ts[NB - 1]; row_ptr[N] = E; }
}

__global__ __launch_bounds__(256) void s3_scatter(const int* __restrict__ src,
                                                  const int* __restrict__ dst,
                                                  const int* __restrict__ mat,
                                                  const int* __restrict__ bb,
                                                  unsigned* __restrict__ coarse, int E)
{
    __shared__ int cur[NB];
    const int tid = threadIdx.x;
    const int* mrow = mat + (size_t)blockIdx.x * NB;
    for (int i = tid; i < NB; i += 256) cur[i] = bb[i] + mrow[i];
    __syncthreads();
    const int e0 = blockIdx.x * EPB;
#pragma unroll
    for (int it = 0; it < EPB / 256; ++it) {
        int e = e0 + it * 256 + tid;
        if (e < E) {
            int d = dst[e];
            int p = atomicAdd(&cur[d >> 7], 1);
            coarse[p] = ((unsigned)src[e] << 7) | (unsigned)(d & 127);
        }
    }
}

__global__ __launch_bounds__(256) void s4_fine(const unsigned* __restrict__ coarse,
                                               const int* __restrict__ bb,
                                               int* __restrict__ row_ptr,
                                               int* __restrict__ srcs, int N)
{
    __shared__ int fcnt[128];
    __shared__ int fs[128];
    __shared__ int cur[128];
    const int tid = threadIdx.x;
    const int b = blockIdx.x;
    const int seg0 = bb[b], seg1 = bb[b + 1];
    if (tid < 128) fcnt[tid] = 0;
    __syncthreads();
    for (int p = seg0 + tid; p < seg1; p += 256)
        atomicAdd(&fcnt[coarse[p] & 127u], 1);
    __syncthreads();
    if (tid < 128) fs[tid] = fcnt[tid];
    __syncthreads();
#pragma unroll
    for (int off = 1; off < 128; off <<= 1) {
        int add = 0;
        if (tid < 128 && tid >= off) add = fs[tid - off];
        __syncthreads();
        if (tid < 128) fs[tid] += add;
        __syncthreads();
    }
    if (tid < 128) {
        int excl = fs[tid] - fcnt[tid];
        cur[tid] = seg0 + excl;
        int d = b * 128 + tid;
        if (d < N) row_ptr[d] = seg0 + excl;
    }
    __syncthreads();
    for (int p = seg0 + tid; p < seg1; p += 256) {
        unsigned v = coarse[p];
        int q = atomicAdd(&cur[v & 127u], 1);
        srcs[q] = (int)(v >> 7);
    }
}

// --------------------------- pull kernels (R9 versions) ---------------------
__global__ __launch_bounds__(256) void pull_h128(const uint2* __restrict__ xh4,
                                                 const int* __restrict__ row_ptr,
                                                 const int* __restrict__ srcs,
                                                 uint2* __restrict__ aggh4, int N)
{
    const int w    = (blockIdx.x * 256 + threadIdx.x) >> 6;
    const int l    = threadIdx.x & 63;
    const int half = l >> 5;
    const int col  = l & 31;
    if (w >= N) return;
    const int beg = row_ptr[w], end = row_ptr[w + 1];
    float a0 = 0.f, a1 = 0.f, a2 = 0.f, a3 = 0.f;
    int j = beg;
    for (; j + 7 < end; j += 8) {
        int s0 = srcs[j + 0 + half], s1 = srcs[j + 2 + half];
        int s2 = srcs[j + 4 + half], s3 = srcs[j + 6 + half];
        uint2 u0 = xh4[(size_t)s0 * 32 + col];
        uint2 u1 = xh4[(size_t)s1 * 32 + col];
        uint2 u2 = xh4[(size_t)s2 * 32 + col];
        uint2 u3 = xh4[(size_t)s3 * 32 + col];
        float2 p;
        p = h2f(u0.x); a0 += p.x; a1 += p.y;  p = h2f(u0.y); a2 += p.x; a3 += p.y;
        p = h2f(u1.x); a0 += p.x; a1 += p.y;  p = h2f(u1.y); a2 += p.x; a3 += p.y;
        p = h2f(u2.x); a0 += p.x; a1 += p.y;  p = h2f(u2.y); a2 += p.x; a3 += p.y;
        p = h2f(u3.x); a0 += p.x; a1 += p.y;  p = h2f(u3.y); a2 += p.x; a3 += p.y;
    }
    for (; j < end; j += 2) {
        int jj = j + half;
        float m = (jj < end) ? 1.f : 0.f;
        int s = srcs[(jj < end) ? jj : (end - 1)];
        uint2 u = xh4[(size_t)s * 32 + col];
        float2 p;
        p = h2f(u.x); a0 += m * p.x; a1 += m * p.y;
        p = h2f(u.y); a2 += m * p.x; a3 += m * p.y;
    }
    a0 += __shfl_xor(a0, 32); a1 += __shfl_xor(a1, 32);
    a2 += __shfl_xor(a2, 32); a3 += __shfl_xor(a3, 32);
    if (half == 0) {
        uint2 o; o.x = f2h(a0, a1); o.y = f2h(a2, a3);
        aggh4[(size_t)w * 32 + col] = o;
    }
}

__global__ __launch_bounds__(256) void pull_add_h64(const uint2* __restrict__ hr4,
                                                    const int* __restrict__ row_ptr,
                                                    const int* __restrict__ srcs,
                                                    float* __restrict__ out, int N)
{
    const int w   = (blockIdx.x * 256 + threadIdx.x) >> 6;
    const int l   = threadIdx.x & 63;
    const int q   = l >> 4;
    const int col = l & 15;
    if (w >= N) return;
    const int beg = row_ptr[w], end = row_ptr[w + 1];
    float a0 = 0.f, a1 = 0.f, a2 = 0.f, a3 = 0.f;
    int j = beg;
    for (; j + 7 < end; j += 8) {
        int s0 = srcs[j + q], s1 = srcs[j + 4 + q];
        uint2 u0 = hr4[(size_t)s0 * 16 + col];
        uint2 u1 = hr4[(size_t)s1 * 16 + col];
        float2 p;
        p = h2f(u0.x); a0 += p.x; a1 += p.y;  p = h2f(u0.y); a2 += p.x; a3 += p.y;
        p = h2f(u1.x); a0 += p.x; a1 += p.y;  p = h2f(u1.y); a2 += p.x; a3 += p.y;
    }
    for (; j < end; j += 4) {
        int jj = j + q;
        float m = (jj < end) ? 1.f : 0.f;
        int s = srcs[(jj < end) ? jj : (end - 1)];
        uint2 u = hr4[(size_t)s * 16 + col];
        float2 p;
        p = h2f(u.x); a0 += m * p.x; a1 += m * p.y;
        p = h2f(u.y); a2 += m * p.x; a3 += m * p.y;
    }
    a0 += __shfl_xor(a0, 16); a1 += __shfl_xor(a1, 16);
    a2 += __shfl_xor(a2, 16); a3 += __shfl_xor(a3, 16);
    a0 += __shfl_xor(a0, 32); a1 += __shfl_xor(a1, 32);
    a2 += __shfl_xor(a2, 32); a3 += __shfl_xor(a3, 32);
    if (q == 0) {
        f4* po = (f4*)out + (size_t)w * 16 + col;
        f4 cur = *po;
        cur[0] += a0; cur[1] += a1; cur[2] += a2; cur[3] += a3;
        *po = cur;
    }
}

// ------ PERSISTENT FUSED MFMA GEMM v5 (weights once + A double-buffer) ------
// 256 blocks x 512 threads (8 waves x 16 rows). Barrier-free tile loop;
// next tile's 8 A-frag loads issue before current tile's MFMA burst.
__global__ __launch_bounds__(512) void mfma_fused(
    const _Float16* __restrict__ aggh, const _Float16* __restrict__ xh,
    const _Float16* __restrict__ wb,   // wr1h@0, wq1h@16384, wr2h@32768, wq2h@40960
    const float* __restrict__ b1, const float* __restrict__ b2,
    _Float16* __restrict__ hrh, float* __restrict__ outp, int N)
{
    __shared__ _Float16 smem[49152 + 8 * 16 * 128];   // 96 KB + 32 KB
    _Float16* lw = smem;
    const int tid = threadIdx.x;
    const int wv = tid >> 6;
    const int l  = tid & 63;
    const int lr = l & 15;
    const int kg = l >> 4;
    _Float16* hb = smem + 49152 + wv * (16 * 128);

    // stage weights global->LDS once: 16B chunk g -> slot ^= (row&15)
#pragma unroll
    for (int it = 0; it < 12; ++it) {
        int g = tid + it * 512;                       // 0..6143
        int d = (g & ~15) | ((g ^ (g >> 4)) & 15);
        *(h8*)&lw[d * 8] = *(const h8*)(wb + (size_t)g * 8);
    }
    __syncthreads();

    const int ntiles = (N + 127) / 128;
    const int ro = kg * 4;

    int t = blockIdx.x;
    // prologue: load tile t's A-frags
    h8 afr[8];
    {
        const int r0 = min(t * 128 + wv * 16 + lr, N - 1);
#pragma unroll
        for (int c = 0; c < 4; ++c) {
            const int k0 = c * 32 + kg * 8;
            afr[c]     = *(const h8*)(aggh + (size_t)r0 * 128 + k0);
            afr[c + 4] = *(const h8*)(xh   + (size_t)r0 * 128 + k0);
        }
    }

    for (; t < ntiles; ) {
        const int base = t * 128 + wv * 16;
        const int tn = t + gridDim.x;
        const int tc = min(tn, ntiles - 1);

        // issue NEXT tile's A-frag loads (hide under this tile's MFMAs)
        h8 nxt[8];
        {
            const int rn = min(tc * 128 + wv * 16 + lr, N - 1);
#pragma unroll
            for (int c = 0; c < 4; ++c) {
                const int k0 = c * 32 + kg * 8;
                nxt[c]     = *(const h8*)(aggh + (size_t)rn * 128 + k0);
                nxt[c + 4] = *(const h8*)(xh   + (size_t)rn * 128 + k0);
            }
        }

        // layer 1: K=256 dual, B from LDS
        f4 acc[8];
#pragma unroll
        for (int n = 0; n < 8; ++n) acc[n] = 0.f;
#pragma unroll
        for (int kk = 0; kk < 8; ++kk) {
            const int R = (kk < 4) ? 0 : 16384;
            const int sl = ((kk & 3) * 4 + kg) ^ lr;  // swizzled 16B slot
#pragma unroll
            for (int n = 0; n < 8; ++n) {
                h8 bf = *(const h8*)&lw[R + (n * 16 + lr) * 128 + (sl << 3)];
                acc[n] = __builtin_amdgcn_mfma_f32_16x16x32_f16(afr[kk], bf, acc[n], 0, 0, 0);
            }
        }

        // relu+bias -> per-wave swizzled h tile (wave-private, no barrier)
#pragma unroll
        for (int n = 0; n < 8; ++n) {
            const int col = n * 16 + lr;
            const float bias = b1[col];
#pragma unroll
            for (int j = 0; j < 4; ++j) {
                const int row = ro + j;
                hb[row * 128 + (col ^ ((row & 7) << 3))] =
                    (_Float16)fmaxf(acc[n][j] + bias, 0.f);
            }
        }

        // layer 2: K=128, A from own h tile, B from LDS
        f4 acc2[8];
#pragma unroll
        for (int n = 0; n < 8; ++n) acc2[n] = 0.f;
#pragma unroll
        for (int kk = 0; kk < 4; ++kk) {
            const int k0 = kk * 32 + kg * 8;
            const int swz = (lr & 7) << 3;
            h8 a0 = *(const h8*)&hb[lr * 128 + (k0 ^ swz)];
            const int sl = (kk * 4 + kg) ^ lr;
#pragma unroll
            for (int n = 0; n < 8; ++n) {
                const int R2 = (n < 4) ? 32768 : 40960;
                h8 bf = *(const h8*)&lw[R2 + ((n & 3) * 16 + lr) * 128 + (sl << 3)];
                acc2[n] = __builtin_amdgcn_mfma_f32_16x16x32_f16(a0, bf, acc2[n], 0, 0, 0);
            }
        }

        // epilogue: cols 0..63 -> hr(f16), 64..127 -> out(f32)+b2
#pragma unroll
        for (int n = 0; n < 8; ++n) {
            const int col = n * 16 + lr;
#pragma unroll
            for (int j = 0; j < 4; ++j) {
                int r = base + ro + j;
                if (r < N) {
                    if (n < 4) {
                        hrh[(size_t)r * 64 + col] = (_Float16)acc2[n][j];
                    } else {
                        outp[(size_t)r * 64 + (col - 64)] = acc2[n][j] + b2[col - 64];
                    }
                }
            }
        }

        // rotate double buffer
#pragma unroll
        for (int c = 0; c < 8; ++c) afr[c] = nxt[c];
        t = tn;
    }
}

extern "C" void kernel_launch(void* const* d_in, const int* in_sizes, int n_in,
                              void* d_out, int out_size, void* d_ws, size_t ws_size,
                              hipStream_t stream)
{
    const float* x       = (const float*)d_in[0];
    const int*   ei      = (const int*)d_in[1];
    const float* w_rel1  = (const float*)d_in[2];
    const float* b_rel1  = (const float*)d_in[3];
    const float* w_root1 = (const float*)d_in[4];
    const float* w_rel2  = (const float*)d_in[5];
    const float* b_rel2  = (const float*)d_in[6];
    const float* w_root2 = (const float*)d_in[7];
    float* out = (float*)d_out;

    const int N = in_sizes[0] / 128;
    const int E = in_sizes[1] / 2;
    const int* src = ei;        // edge_index[0]
    const int* dst = ei + E;    // edge_index[1]

    // workspace (~67 MB):
    //   xh [N*128 h] | aggh [N*128 h] (hrh aliases) | wbuf [49152 h]
    //   | srcs [E] | coarse [E u32] | mat [nblk*NB] | tot [NB] | bb [NB+1]
    //   | row_ptr [N+1]
    _Float16* xh    = (_Float16*)d_ws;
    _Float16* aggh  = xh + (size_t)N * 128;
    _Float16* hrh   = aggh;                         // alias: aggh dead after gemm
    _Float16* wbuf  = aggh + (size_t)N * 128;
    int*      srcs    = (int*)(wbuf + 49152);
    unsigned* coarse  = (unsigned*)(srcs + E);
    const int nblk    = (E + EPB - 1) / EPB;        // <= 512 (E <= 2M)
    int*      mat     = (int*)(coarse + E);         // nblk*NB
    int*      tot     = mat + (size_t)nblk * NB;    // NB
    int*      bb      = tot + NB;                   // NB+1
    int*      row_ptr = bb + (NB + 1);              // N+1

    // ---- prep: hist + xcast + wcast fused ----
    prep_fused<<<nblk, 256, 0, stream>>>(dst, mat, x, xh,
                                         w_rel1, w_root1, w_rel2, w_root2,
                                         wbuf, E, (long)N * 16);

    // ---- CSR build (rest) ----
    s2_colscan<<<NB, 512, 0, stream>>>(mat, tot, nblk);
    s2b_base  <<<1, NB, 0, stream>>>(tot, bb, row_ptr, N, E);
    s3_scatter<<<nblk, 256, 0, stream>>>(src, dst, mat, bb, coarse, E);
    s4_fine   <<<NB, 256, 0, stream>>>(coarse, bb, row_ptr, srcs, N);

    // 1. aggh = pull-sum xh
    pull_h128<<<(N * 64 + 255) / 256, 256, 0, stream>>>(
        (const uint2*)xh, row_ptr, srcs, (uint2*)aggh, N);

    // 2. persistent fused GEMMs
    mfma_fused<<<256, 512, 0, stream>>>(
        aggh, xh, wbuf, b_rel1, b_rel2, hrh, out, N);

    // 3. out += pull-sum hr
    pull_add_h64<<<(N * 64 + 255) / 256, 256, 0, stream>>>(
        (const uint2*)hrh, row_ptr, srcs, out, N);
}